// Round 7
// baseline (465.002 us; speedup 1.0000x reference)
//
#include <hip/hip_runtime.h>
#include <math.h>

// Problem dims (fixed by reference)
#define BB 32
#define DD 256
#define TT 1024
#define KK 1024
#define NN (BB*TT)          // 32768 rows

#define BROWS 64            // rows per block (= 64 lanes)
#define NSTEP 32            // 4 sub-chunks x 8 d-steps of 32

// ws layout (elements): float wsq[1024] @0 ; int counts[1024] @1024 ; float sse @2048

// wsq[k] = sum_d W[k,d]^2 (fp64 accumulate, round once). Zeroes counts+sse.
__global__ void prep_kernel(const float* __restrict__ W, float* __restrict__ wsq,
                            int* __restrict__ counts, float* __restrict__ sse) {
    const int k = blockIdx.x;          // 1024 blocks, 64 threads
    const int lane = threadIdx.x;
    const float4 v = ((const float4*)(W + (size_t)k * DD))[lane];
    double s = (double)v.x * v.x + (double)v.y * v.y + (double)v.z * v.z + (double)v.w * v.w;
    #pragma unroll
    for (int m = 32; m > 0; m >>= 1) s += __shfl_down(s, m);
    if (lane == 0) wsq[k] = (float)s;
    if (blockIdx.x < 16) counts[blockIdx.x * 64 + lane] = 0;
    if (blockIdx.x == 0 && lane == 0) *sse = 0.0f;
}

// async global->LDS, 16B/lane; LDS dest = wave-uniform base + lane*16 (linear).
__device__ __forceinline__ void gl_lds16(const float* g, void* l) {
    __builtin_amdgcn_global_load_lds((const __attribute__((address_space(1))) void*)g,
                                     (__attribute__((address_space(3))) void*)l, 16, 0, 0);
}

// Fused VQ kernel, lane=row mapping:
//  - 256 threads = 4 waves; block owns 64 rows (t-contiguous); lane = row.
//  - wave w owns codes [w*256, (w+1)*256) in 4 sub-chunks of 64 -> acc[64]/thread.
//  - z slab (shared, 16 KB): [64 rows][16 slots of 4d], slot XOR (row&7); per-lane
//    b128 reads are 2-way aliased (free). Re-staged per 64 d (2 barriers / 2 steps).
//  - W slabs (per-wave private, 4 x 2 x 8 KB = 64 KB): [64 codes][8 slots], LINEAR;
//    all reads are wave-uniform broadcasts (conflict-free, base+imm offsets);
//    staged by gl_lds, double-buffered, self-paced vmcnt(0) (no barriers for W).
// dist mirrors np: s1 = fl(rowsq+wsq); v = fmaf(-2, dot, s1). Per-(row,code) dot:
// single sequential fmaf chain d=0..255 in order (steps asc, slots asc, x/y/z/w) —
// bitwise-matches BLAS k-order; validated absmax==0.0 in R1/R2/R3/R5/R6. DO NOT
// reorder. acc[] statically indexed only (rule #20); dq-loop stays rolled (R4).
__global__ __launch_bounds__(256, 2) void vq_fused_kernel(
    const float* __restrict__ z, const float* __restrict__ W,
    const float* __restrict__ wsq, float* __restrict__ out,
    int* __restrict__ counts, float* __restrict__ sse)
{
    __shared__ float4 zs[BROWS * 16];       // 16 KB shared z slab (+ scratch at end)
    __shared__ float4 wsl[4][2][64 * 8];    // 64 KB per-wave W double buffers
    const int tid = threadIdx.x;
    const int w = tid >> 6, lane = tid & 63;
    const int row0 = blockIdx.x * BROWS;
    const int b = row0 >> 10, t0 = row0 & 1023;
    const size_t bbase = (size_t)b * DD * TT;
    const float* zbase = z + bbase + t0;

    // staging identities
    const int zq0 = w * 4;           // z slots: 4 per thread (of 16)
    float4 zreg[4];

    // ---- prologue: issue W stage (t=0) + z slab (d 0..63); latency hides under rowsq
    {
        const int cb = w * 256;      // sub-chunk 0, d0 = 0
        char* dst = (char*)&wsl[w][0][0];
        #pragma unroll
        for (int k = 0; k < 8; ++k)
            gl_lds16(W + (size_t)(cb + k * 8 + (lane >> 3)) * DD + (lane & 7) * 4,
                     dst + k * 1024);
        #pragma unroll
        for (int j = 0; j < 4; ++j) {
            const float* zp = zbase + (size_t)((zq0 + j) * 4) * TT + lane;
            zreg[j].x = zp[0]; zreg[j].y = zp[(size_t)TT];
            zreg[j].z = zp[(size_t)2 * TT]; zreg[j].w = zp[(size_t)3 * TT];
        }
    }

    // ---- rowsq: EXACT R6 computation (fp64 64-d chains per quarter, (g0+g1)+(g2+g3))
    float rsq;
    {
        const int ro = lane & 15;          // row offset within wave's 16 rows
        const int g  = lane >> 4;          // d-quarter 0..3
        const float* zp = zbase + (size_t)g * 64 * TT + (16 * w + ro);
        double s = 0.0;
        #pragma unroll 4
        for (int d = 0; d < 64; ++d) { float v = zp[(size_t)d * TT]; s += (double)v * v; }
        s += __shfl_xor(s, 16);            // fp64 add commutative: bitwise safe
        s += __shfl_xor(s, 32);
        float f = (float)s;
        __syncthreads();
        if (lane < 16) ((float*)zs)[16 * w + lane] = f;   // row 16w+lane
        __syncthreads();
        rsq = ((float*)zs)[lane];          // my row's rowsq (exact copy)
        __syncthreads();                   // protect scratch until first z write
    }

    float minv = 3.4e38f; int mini = 0;
    float acc[64];

    for (int t = 0; t < NSTEP; ++t) {
        const int c = t >> 3, dd = t & 7, h = t & 1;
        if (h == 0) {
            __syncthreads();   // sync_A: all waves done reading zs (prev slab)
            #pragma unroll
            for (int j = 0; j < 4; ++j)
                zs[(lane << 4) | ((zq0 + j) ^ (lane & 7))] = zreg[j];
            __syncthreads();   // sync_B: z slab visible
            if (t + 2 < NSTEP) {   // prefetch next slab's z into regs (lands by next pair)
                const int d0n = ((t + 2) & 7) * 32;
                #pragma unroll
                for (int j = 0; j < 4; ++j) {
                    const float* zp = zbase + (size_t)(d0n + (zq0 + j) * 4) * TT + lane;
                    zreg[j].x = zp[0]; zreg[j].y = zp[(size_t)TT];
                    zreg[j].z = zp[(size_t)2 * TT]; zreg[j].w = zp[(size_t)3 * TT];
                }
            }
        }
        // W[t&1] was staged a full compute phase ago (or drained by the barriers):
        // this wait is ~free but makes the gl_lds->ds_read hazard explicit.
        asm volatile("s_waitcnt vmcnt(0)" ::: "memory");
        // issue next step's W stage into the other buffer; lands during compute
        if (t + 1 < NSTEP) {
            const int tn = t + 1;
            const int cbn = w * 256 + (tn >> 3) * 64, d0n = (tn & 7) * 32;
            char* dst = (char*)&wsl[w][tn & 1][0];
            #pragma unroll
            for (int k = 0; k < 8; ++k)
                gl_lds16(W + (size_t)(cbn + k * 8 + (lane >> 3)) * DD + d0n + (lane & 7) * 4,
                         dst + k * 1024);
        }
        if (dd == 0) {
            #pragma unroll
            for (int j = 0; j < 64; ++j) acc[j] = 0.0f;
        }
        // compute: 8 slots x (1 per-lane z read + 64 uniform W reads + 256 fmaf)
        const float4* wb = &wsl[w][h][0];
        #pragma clang loop unroll(disable)
        for (int dq = 0; dq < 8; ++dq) {
            const int dqg = (h << 3) | dq;                       // slot in z slab
            float4 z4 = zs[(lane << 4) | (dqg ^ (lane & 7))];
            const float4* wp = wb + dq;
            #pragma unroll
            for (int j = 0; j < 64; ++j) {
                float4 wf = wp[j * 8];                           // uniform broadcast
                acc[j] = fmaf(z4.x, wf.x, acc[j]);
                acc[j] = fmaf(z4.y, wf.y, acc[j]);
                acc[j] = fmaf(z4.z, wf.z, acc[j]);
                acc[j] = fmaf(z4.w, wf.w, acc[j]);
            }
        }
        if (dd == 7) {
            // score + running argmin (codes ascending; strict < = first-min like np)
            const int cb = w * 256 + c * 64;
            const float* wqp = wsq + cb;
            #pragma unroll
            for (int j = 0; j < 64; ++j) {
                float s1 = rsq + wqp[j];                 // rounding 1 (np A+B)
                float v = fmaf(-2.0f, acc[j], s1);       // rounding 2 (np (A+B)-2P)
                if (v < minv) { minv = v; mini = cb + j; }
            }
        }
    }

    // ---- cross-wave argmin reduce (waves ascending -> lowest code on ties)
    __syncthreads();                       // all compute done; zs becomes scratch
    float* cand_v = (float*)zs;            // [4][64]
    int*   cand_i = (int*)zs + 256;        // [4][64]
    int*   idxs   = (int*)zs + 512;        // [64]
    float* ssescr = (float*)zs + 640;      // [4]
    cand_v[w * 64 + lane] = minv;
    cand_i[w * 64 + lane] = mini;
    __syncthreads();
    if (tid < 64) {
        float bv = cand_v[tid]; int bi = cand_i[tid];
        #pragma unroll
        for (int ww = 1; ww < 4; ++ww) {
            float v = cand_v[ww * 64 + tid];
            int  ii = cand_i[ww * 64 + tid];
            if (v < bv) { bv = v; bi = ii; }             // strict: lower wave wins ties
        }
        idxs[tid] = bi;
        atomicAdd(&counts[bi], 1);
    }
    __syncthreads();

    // ---- fused gather / straight-through / SSE over this block's 64 rows x 256 d
    const int tg = tid & 15;       // t-quarter (4 rows)
    const int dg = tid >> 4;       // 16 d-groups of 16
    const int t4 = tg * 4;
    int ixs[4];
    #pragma unroll
    for (int m = 0; m < 4; ++m) ixs[m] = idxs[t4 + m];
    float ssel = 0.0f;
    #pragma unroll
    for (int k4 = 0; k4 < 4; ++k4) {
        const int d0 = dg * 16 + k4 * 4;
        float wr[4][4];
        #pragma unroll
        for (int m = 0; m < 4; ++m) {
            float4 wv = *(const float4*)(W + (size_t)ixs[m] * DD + d0);
            wr[m][0] = wv.x; wr[m][1] = wv.y; wr[m][2] = wv.z; wr[m][3] = wv.w;
        }
        #pragma unroll
        for (int dd = 0; dd < 4; ++dd) {
            const int d = d0 + dd;
            const size_t base = bbase + (size_t)d * TT + t0 + t4;
            float4 zv = *(const float4*)(z + base);
            float e0 = wr[0][dd] - zv.x, e1 = wr[1][dd] - zv.y;
            float e2 = wr[2][dd] - zv.z, e3 = wr[3][dd] - zv.w;
            float4 o;
            o.x = zv.x + e0; o.y = zv.y + e1; o.z = zv.z + e2; o.w = zv.w + e3;
            *(float4*)(out + base) = o;
            ssel += (e0 * e0 + e1 * e1) + (e2 * e2 + e3 * e3);
        }
    }
    #pragma unroll
    for (int m = 32; m > 0; m >>= 1) ssel += __shfl_down(ssel, m);
    if (lane == 0) ssescr[w] = ssel;
    __syncthreads();
    if (tid == 0) atomicAdd(sse, (ssescr[0] + ssescr[1]) + (ssescr[2] + ssescr[3]));
}

// reg_loss = 1.25 * sse / numel ; perplexity = exp(-sum p*log(p+1e-10))
__global__ void finalize_kernel(const int* __restrict__ counts, const float* __restrict__ sse,
                                float* __restrict__ out) {
    float s = 0.0f;
    for (int k = threadIdx.x; k < KK; k += 256) {
        float p = (float)counts[k] / (float)NN;
        s += p * logf(p + 1e-10f);
    }
    #pragma unroll
    for (int m = 32; m > 0; m >>= 1) s += __shfl_down(s, m);
    __shared__ float wsum[4];
    if ((threadIdx.x & 63) == 0) wsum[threadIdx.x >> 6] = s;
    __syncthreads();
    if (threadIdx.x == 0) {
        float ent = (wsum[0] + wsum[1]) + (wsum[2] + wsum[3]);
        out[(size_t)BB * DD * TT]     = 1.25f * (*sse) / (float)(BB * DD * TT);
        out[(size_t)BB * DD * TT + 1] = expf(-ent);
    }
}

extern "C" void kernel_launch(void* const* d_in, const int* in_sizes, int n_in,
                              void* d_out, int out_size, void* d_ws, size_t ws_size,
                              hipStream_t stream) {
    const float* z = (const float*)d_in[0];   // (32, 256, 1024) fp32
    const float* W = (const float*)d_in[1];   // (1024, 256) fp32
    float* out = (float*)d_out;               // 8388608 + 2 fp32

    float* wsq    = (float*)d_ws;
    int*   counts = (int*)(wsq + 1024);
    float* sse    = (float*)(counts + 1024);

    prep_kernel<<<1024, 64, 0, stream>>>(W, wsq, counts, sse);
    vq_fused_kernel<<<NN / BROWS, 256, 0, stream>>>(z, W, wsq, out, counts, sse);
    finalize_kernel<<<1, 256, 0, stream>>>(counts, sse, out);
}

// Round 8
// 306.884 us; speedup vs baseline: 1.5152x; 1.5152x over previous
//
#include <hip/hip_runtime.h>
#include <math.h>

// Problem dims (fixed by reference)
#define BB 32
#define DD 256
#define TT 1024
#define KK 1024
#define NN (BB*TT)          // 32768 rows

#define BROWS 128           // rows per block
#define CCH   256           // codes per chunk
#define NSTEP 32            // 4 chunks x 8 d-steps of 32

// ws layout (elements): float wsq[1024] @0 ; int counts[1024] @1024 ; float sse @2048

// wsq[k] = sum_d W[k,d]^2 (fp64 accumulate, round once). Zeroes counts+sse.
__global__ void prep_kernel(const float* __restrict__ W, float* __restrict__ wsq,
                            int* __restrict__ counts, float* __restrict__ sse) {
    const int k = blockIdx.x;          // 1024 blocks, 64 threads
    const int lane = threadIdx.x;
    const float4 v = ((const float4*)(W + (size_t)k * DD))[lane];
    double s = (double)v.x * v.x + (double)v.y * v.y + (double)v.z * v.z + (double)v.w * v.w;
    #pragma unroll
    for (int m = 32; m > 0; m >>= 1) s += __shfl_down(s, m);
    if (lane == 0) wsq[k] = (float)s;
    if (blockIdx.x < 16) counts[blockIdx.x * 64 + lane] = 0;
    if (blockIdx.x == 0 && lane == 0) *sse = 0.0f;
}

// async global->LDS, 16B/lane; LDS dest = wave-uniform base + lane*16 (linear).
__device__ __forceinline__ void gl_lds16(const float* g, void* l) {
    __builtin_amdgcn_global_load_lds((const __attribute__((address_space(1))) void*)g,
                                     (__attribute__((address_space(3))) void*)l, 16, 0, 0);
}

// Fused VQ kernel. 256 thr = 8(ty) x 32(tx); per-thread tile 16 rows x 8 codes
// (acc[128]); 1 wave/SIMD by design -> __launch_bounds__(256,1) lifts VGPR cap
// to 512 (no spill). LDS-pipe budget per step ~56% of FMA issue (R7 lesson:
// LDS instruction issue was co-limiting at 8x8 tiles; 16x8 halves reads/fmaf).
//  - z slab zst[8 slots][128 rows] (16 KB, transposed): zf reads = base+imm,
//    wave-broadcast (2 addrs); writes 2-way bank (free), no XOR needed.
//  - W slab ws[2][256 codes][8 slots] (64 KB dbuf): R6 scheme verbatim —
//    gl_lds linear dest + pre-swizzled source (slot q of code c at q^((c>>3)&7)),
//    reads 2-way bank (free), self-paced vmcnt(0) that only waits loads issued
//    one full step earlier.
// dist mirrors np: s1 = fl(rowsq+wsq); v = fmaf(-2, dot, s1). Per-(row,code)
// dot: single sequential fmaf chain d=0..255 in order (steps asc, q asc,
// x/y/z/w) — bitwise-matches BLAS k-order; validated absmax==0.0 in
// R1/R2/R3/R5/R6/R7. DO NOT reorder. acc static-indexed only (rule #20);
// q-loop stays rolled (R4 spill lesson).
__global__ __launch_bounds__(256, 1) void vq_fused_kernel(
    const float* __restrict__ z, const float* __restrict__ W,
    const float* __restrict__ wsq, float* __restrict__ out,
    int* __restrict__ counts, float* __restrict__ sse)
{
    __shared__ float4 zst[8][BROWS];    // 16 KB [slot][row]; scratch pre/post loop
    __shared__ float4 ws[2][CCH * 8];   // 64 KB W double buffer
    const int tid = threadIdx.x;
    const int tx = tid & 31, ty = tid >> 5;
    const int w = tid >> 6, lane = tid & 63;
    const int txc = tx & 7;
    const int zr = tid & 127, hh = tid >> 7;   // z staging: row, slot-half
    const int row0 = blockIdx.x * BROWS;
    const int b = row0 >> 10, t0 = row0 & 1023;
    const size_t bbase = (size_t)b * DD * TT;
    const float* zbase = z + bbase + t0;

    float4 zreg[4];

    // ---- prologue: issue W stage (step 0) + z regs (step 0); hides under rowsq
    {
        char* dst = (char*)&ws[0][0] + (size_t)w * 8192;
        #pragma unroll
        for (int k = 0; k < 8; ++k) {
            const int r = w * 64 + k * 8 + (lane >> 3);
            gl_lds16(W + (size_t)r * DD + 4 * ((lane & 7) ^ k), dst + k * 1024);
        }
        #pragma unroll
        for (int j = 0; j < 4; ++j) {
            const float* zp = zbase + (size_t)((hh * 4 + j) * 4) * TT + zr;
            zreg[j].x = zp[0]; zreg[j].y = zp[(size_t)TT];
            zreg[j].z = zp[(size_t)2 * TT]; zreg[j].w = zp[(size_t)3 * TT];
        }
    }

    // ---- rowsq: per row, 4 fp64 64-d chains, tree ((g0+g1)+(g2+g3)) — bitwise
    // identical to the validated R6 computation (thread does chains 2hh, 2hh+1).
    float rsq[16];
    {
        double* pscr = (double*)&zst[0][0];        // [2][128] doubles (2 KB)
        float*  fscr = (float*)&zst[4][0];         // 128 floats (at byte 8192)
        const float* zp = zbase + (size_t)(2 * hh) * 64 * TT + zr;
        double sA = 0.0, sB = 0.0;
        #pragma unroll 4
        for (int d = 0; d < 64; ++d) { float v = zp[(size_t)d * TT]; sA += (double)v * v; }
        const float* zp2 = zp + (size_t)64 * TT;
        #pragma unroll 4
        for (int d = 0; d < 64; ++d) { float v = zp2[(size_t)d * TT]; sB += (double)v * v; }
        pscr[hh * 128 + zr] = sA + sB;             // (g0+g1) or (g2+g3)
        __syncthreads();
        if (tid < 128) fscr[tid] = (float)(pscr[tid] + pscr[128 + tid]);
        __syncthreads();
        #pragma unroll
        for (int i = 0; i < 16; ++i) rsq[i] = fscr[ty * 16 + i];
        // sync_A at t=0 protects scratch before the first zst write
    }

    float minv[16]; int mini[16];
    #pragma unroll
    for (int i = 0; i < 16; ++i) { minv[i] = 3.4e38f; mini[i] = 0; }

    float acc[16][8];
    float wq[8];

    for (int t = 0; t < NSTEP; ++t) {
        const int sl = t & 7, ch = t >> 3, h = t & 1;
        __syncthreads();   // sync_A: all waves done reading zst (and rowsq scratch)
        // write z slab for this step (zreg loaded one step ago; auto vmcnt wait)
        #pragma unroll
        for (int j = 0; j < 4; ++j) zst[hh * 4 + j][zr] = zreg[j];
        __syncthreads();   // sync_B: z slab visible; only ds_writes drained
        // W[h] was staged one full step ago -> this wait is ~free
        asm volatile("s_waitcnt vmcnt(0)" ::: "memory");
        // issue next step's staging NOW; lands during compute below
        if (t + 1 < NSTEP) {
            const int tn = t + 1, chn = tn >> 3, sln = tn & 7;
            const float* wch = W + (size_t)(chn * CCH) * DD + sln * 32;
            char* dst = (char*)&ws[tn & 1][0] + (size_t)w * 8192;
            #pragma unroll
            for (int k = 0; k < 8; ++k) {
                const int r = w * 64 + k * 8 + (lane >> 3);
                gl_lds16(wch + (size_t)r * DD + 4 * ((lane & 7) ^ k), dst + k * 1024);
            }
            #pragma unroll
            for (int j = 0; j < 4; ++j) {
                const float* zp = zbase + (size_t)(sln * 32 + (hh * 4 + j) * 4) * TT + zr;
                zreg[j].x = zp[0]; zreg[j].y = zp[(size_t)TT];
                zreg[j].z = zp[(size_t)2 * TT]; zreg[j].w = zp[(size_t)3 * TT];
            }
        }
        if (sl == 0) {
            #pragma unroll
            for (int i = 0; i < 16; ++i)
                #pragma unroll
                for (int j = 0; j < 8; ++j) acc[i][j] = 0.0f;
            #pragma unroll
            for (int j = 0; j < 8; ++j) wq[j] = wsq[ch * CCH + tx * 8 + j];
        }
        // 16x8x(32d) register-tile FMA; d-order: q ascending, then x,y,z,w
        const float4* wb0 = &ws[h][tx * 64];
        #pragma clang loop unroll(disable)
        for (int q = 0; q < 8; ++q) {
            const float4* wp = wb0 + (q ^ txc);
            float4 wf[8];
            #pragma unroll
            for (int j = 0; j < 8; ++j) wf[j] = wp[j * 8];
            #pragma unroll
            for (int i = 0; i < 16; ++i) {
                float4 z4 = zst[q][ty * 16 + i];    // broadcast, base+imm
                #pragma unroll
                for (int j = 0; j < 8; ++j) {
                    acc[i][j] = fmaf(z4.x, wf[j].x, acc[i][j]);
                    acc[i][j] = fmaf(z4.y, wf[j].y, acc[i][j]);
                    acc[i][j] = fmaf(z4.z, wf[j].z, acc[i][j]);
                    acc[i][j] = fmaf(z4.w, wf[j].w, acc[i][j]);
                }
            }
        }
        if (sl == 7) {
            // score + running argmin (codes ascending -> first-min like np.argmin)
            #pragma unroll
            for (int j = 0; j < 8; ++j) {
                const int c = ch * CCH + tx * 8 + j;
                #pragma unroll
                for (int i = 0; i < 16; ++i) {
                    float s1 = rsq[i] + wq[j];               // rounding 1 (np A+B)
                    float v = fmaf(-2.0f, acc[i][j], s1);    // rounding 2 (np (A+B)-2P)
                    if (v < minv[i]) { minv[i] = v; mini[i] = c; }
                }
            }
        }
    }

    __syncthreads();                   // all compute done; zst becomes scratch
    int* idxs = (int*)&zst[0][0];      // 128 ints
    float* ssescr = (float*)&zst[0][0] + 256;   // 4 floats (offset 1 KB)
    // reduce across the 32 tx lanes of each row (aligned half-wave); ties -> lowest
    #pragma unroll
    for (int i = 0; i < 16; ++i) {
        float v = minv[i]; int ix = mini[i];
        #pragma unroll
        for (int m = 1; m < 32; m <<= 1) {
            float ov = __shfl_xor(v, m);
            int   oi = __shfl_xor(ix, m);
            if (ov < v || (ov == v && oi < ix)) { v = ov; ix = oi; }
        }
        if (tx == 0) {
            idxs[ty * 16 + i] = ix;
            atomicAdd(&counts[ix], 1);
        }
    }
    __syncthreads();

    // ---- fused gather / straight-through / SSE over this block's 128 rows x 256 d
    const int tg = tid & 31;       // 32 t-groups of 4 rows
    const int dg = tid >> 5;       // 8 d-groups of 32
    const int t4 = tg * 4;
    int ixs[4];
    #pragma unroll
    for (int m = 0; m < 4; ++m) ixs[m] = idxs[t4 + m];
    float ssel = 0.0f;
    #pragma unroll
    for (int k4 = 0; k4 < 8; ++k4) {
        const int d0 = dg * 32 + k4 * 4;
        float wr[4][4];
        #pragma unroll
        for (int m = 0; m < 4; ++m) {
            float4 wv = *(const float4*)(W + (size_t)ixs[m] * DD + d0);
            wr[m][0] = wv.x; wr[m][1] = wv.y; wr[m][2] = wv.z; wr[m][3] = wv.w;
        }
        #pragma unroll
        for (int dd = 0; dd < 4; ++dd) {
            const int d = d0 + dd;
            const size_t base = bbase + (size_t)d * TT + t0 + t4;
            float4 zv = *(const float4*)(z + base);
            float e0 = wr[0][dd] - zv.x, e1 = wr[1][dd] - zv.y;
            float e2 = wr[2][dd] - zv.z, e3 = wr[3][dd] - zv.w;
            float4 o;
            o.x = zv.x + e0; o.y = zv.y + e1; o.z = zv.z + e2; o.w = zv.w + e3;
            *(float4*)(out + base) = o;
            ssel += (e0 * e0 + e1 * e1) + (e2 * e2 + e3 * e3);
        }
    }
    #pragma unroll
    for (int m = 32; m > 0; m >>= 1) ssel += __shfl_down(ssel, m);
    if (lane == 0) ssescr[w] = ssel;
    __syncthreads();
    if (tid == 0) atomicAdd(sse, (ssescr[0] + ssescr[1]) + (ssescr[2] + ssescr[3]));
}

// reg_loss = 1.25 * sse / numel ; perplexity = exp(-sum p*log(p+1e-10))
__global__ void finalize_kernel(const int* __restrict__ counts, const float* __restrict__ sse,
                                float* __restrict__ out) {
    float s = 0.0f;
    for (int k = threadIdx.x; k < KK; k += 256) {
        float p = (float)counts[k] / (float)NN;
        s += p * logf(p + 1e-10f);
    }
    #pragma unroll
    for (int m = 32; m > 0; m >>= 1) s += __shfl_down(s, m);
    __shared__ float wsum[4];
    if ((threadIdx.x & 63) == 0) wsum[threadIdx.x >> 6] = s;
    __syncthreads();
    if (threadIdx.x == 0) {
        float ent = (wsum[0] + wsum[1]) + (wsum[2] + wsum[3]);
        out[(size_t)BB * DD * TT]     = 1.25f * (*sse) / (float)(BB * DD * TT);
        out[(size_t)BB * DD * TT + 1] = expf(-ent);
    }
}

extern "C" void kernel_launch(void* const* d_in, const int* in_sizes, int n_in,
                              void* d_out, int out_size, void* d_ws, size_t ws_size,
                              hipStream_t stream) {
    const float* z = (const float*)d_in[0];   // (32, 256, 1024) fp32
    const float* W = (const float*)d_in[1];   // (1024, 256) fp32
    float* out = (float*)d_out;               // 8388608 + 2 fp32

    float* wsq    = (float*)d_ws;
    int*   counts = (int*)(wsq + 1024);
    float* sse    = (float*)(counts + 1024);

    prep_kernel<<<1024, 64, 0, stream>>>(W, wsq, counts, sse);
    vq_fused_kernel<<<NN / BROWS, 256, 0, stream>>>(z, W, wsq, out, counts, sse);
    finalize_kernel<<<1, 256, 0, stream>>>(counts, sse, out);
}